// Round 10
// baseline (55.455 us; speedup 1.0000x reference)
//
#include <hip/hip_runtime.h>
#include <hip/hip_bf16.h>
#include <stdint.h>

#define NDIM 4096
#define CDIM 64
#define NSPLIT 8
#define SPAN (NDIM / NSPLIT)   // 512 keys per split
#define LOG2E 1.44269504088896f

typedef float f32x16 __attribute__((ext_vector_type(16)));
typedef short bf16x8 __attribute__((ext_vector_type(8)));
union U4B { uint4 u; bf16x8 b; };

// single-instruction packed f32->bf16 (RNE), lo -> bits[15:0], hi -> bits[31:16]
static __device__ __forceinline__ uint32_t cvtpk(float lo, float hi) {
  uint32_t r;
  asm("v_cvt_pk_bf16_f32 %0, %1, %2" : "=v"(r) : "v"(lo), "v"(hi));
  return r;
}
static __device__ __forceinline__ uint16_t f2bf(float f) {
  uint32_t r;
  asm("v_cvt_pk_bf16_f32 %0, %1, %1" : "=v"(r) : "v"(f));
  return (uint16_t)r;
}
static __device__ __forceinline__ float fexp2(float x) {
  return __builtin_amdgcn_exp2f(x);   // raw v_exp_f32
}

// ---------------- Kernel 1: projections via MFMA (fp32 -> bf16) -------------
// 512 blocks x 256 threads (4 waves). Block = (b, 32 columns); wave roles:
// w0: V rows 0-31, w1: V rows 32-63, w2: Q (from x_opt), w3: K (from x_sar).
__global__ __launch_bounds__(256) void proj_kernel(
    const float* __restrict__ x_opt, const float* __restrict__ x_sar,
    const float* __restrict__ wq, const float* __restrict__ bq,
    const float* __restrict__ wk, const float* __restrict__ bk,
    const float* __restrict__ wvp, const float* __restrict__ bv,
    uint16_t* __restrict__ qf, uint16_t* __restrict__ kf,
    uint16_t* __restrict__ vf)
{
  const int tid = threadIdx.x;
  const int w = tid >> 6;       // wave role
  const int l = tid & 63;
  const int x = l & 31;
  const int hi = l >> 5;

  const int id = blockIdx.x;
  const int b = id >> 7;
  const int n0 = (id & 127) * 32;
  const size_t xbase = (size_t)b * CDIM * NDIM;

  // ---- X B-fragment (lane = col n0+x, regs = 8 k along kc*16 + 8hi + j)
  const float* xsrc = (w == 2) ? x_opt : x_sar;
  bf16x8 xB[4];
#pragma unroll
  for (int kc = 0; kc < 4; kc++) {
    float sv[8];
#pragma unroll
    for (int j = 0; j < 8; j++)
      sv[j] = xsrc[xbase + (size_t)(kc * 16 + hi * 8 + j) * NDIM + n0 + x];
    U4B us;
    us.u = make_uint4(cvtpk(sv[0], sv[1]), cvtpk(sv[2], sv[3]),
                      cvtpk(sv[4], sv[5]), cvtpk(sv[6], sv[7]));
    xB[kc] = us.b;
  }

  // ---- W A-fragment
  bf16x8 aF[4];
#pragma unroll
  for (int kc = 0; kc < 4; kc++) {
    U4B ua;
    ua.u = make_uint4(0u, 0u, 0u, 0u);
    if (w < 2) {
      const float* wr = wvp + (w * 32 + x) * 64 + kc * 16 + hi * 8;
      float4 wa = ((const float4*)wr)[0];
      float4 wb = ((const float4*)wr)[1];
      ua.u = make_uint4(cvtpk(wa.x, wa.y), cvtpk(wa.z, wa.w),
                        cvtpk(wb.x, wb.y), cvtpk(wb.z, wb.w));
    } else if (x < 8) {
      const float* wr = ((w == 2) ? wq : wk) + x * 64 + kc * 16 + hi * 8;
      float4 wa = ((const float4*)wr)[0];
      float4 wb = ((const float4*)wr)[1];
      ua.u = make_uint4(cvtpk(wa.x, wa.y), cvtpk(wa.z, wa.w),
                        cvtpk(wb.x, wb.y), cvtpk(wb.z, wb.w));
    }
    aF[kc] = ua.b;
  }

  const f32x16 z16 = {0.f,0.f,0.f,0.f, 0.f,0.f,0.f,0.f,
                      0.f,0.f,0.f,0.f, 0.f,0.f,0.f,0.f};
  f32x16 acc = z16;
#pragma unroll
  for (int kc = 0; kc < 4; kc++)
    acc = __builtin_amdgcn_mfma_f32_32x32x16_bf16(aF[kc], xB[kc], acc, 0, 0, 0);

  if (w < 2) {
    // V stores: C/D lane = col, row = (r&3)+8*(r>>2)+4hi
#pragma unroll
    for (int r = 0; r < 16; r++) {
      const int row = w * 32 + (r & 3) + 8 * (r >> 2) + 4 * hi;
      vf[(size_t)(b * 64 + row) * NDIM + n0 + x] = f2bf(acc[r] + bv[row]);
    }
  } else {
    // Q/K stores: regs 0-3 hold d = 4hi + r; layout [n][16], zero upper 8
    const float* bias = (w == 2) ? bq : bk;
    const float scl = (w == 2) ? LOG2E : 1.0f;   // q pre-scaled for exp2
    float gv[4];
#pragma unroll
    for (int r = 0; r < 4; r++) gv[r] = (acc[r] + bias[4 * hi + r]) * scl;
    uint16_t* dst = (w == 2) ? qf : kf;
    const size_t nrow = ((size_t)b * NDIM + n0 + x) * 16;
    uint2 st;
    st.x = cvtpk(gv[0], gv[1]); st.y = cvtpk(gv[2], gv[3]);
    *(uint2*)(dst + nrow + hi * 4) = st;
    if (hi == 0) {
      const uint4 z4 = make_uint4(0u, 0u, 0u, 0u);
      *(uint4*)(dst + nrow + 8) = z4;
    }
  }
}

// ------------- Kernel 2: flash attention partial (K-split) -----------
// 1024 blocks x 256 threads, sp = id&7 pins KV span to one XCD's L2.
// NO LDS, NO barriers: each wave independently streams K and V fragments
// from L2 with a 1-quarter register lookahead. All quarter/key offsets are
// compile-time constants folding into load immediates.
__global__ __launch_bounds__(256, 4) void attn_kernel(
    const uint16_t* __restrict__ qf, const uint16_t* __restrict__ kf,
    const uint16_t* __restrict__ vf,
    uint16_t* __restrict__ po, float* __restrict__ ls)
{
  const int tid = threadIdx.x;
  const int w = tid >> 6;
  const int l = tid & 63;
  const int x = l & 31;       // query col (S,O) / key row (K-frag) / channel (V-frag)
  const int hi = l >> 5;

  const int id = blockIdx.x;
  const int sp = id & 7;
  const int qb = (id >> 3) & 31;
  const int b = id >> 8;

  const int n0 = qb * 128;
  const int qrow = n0 + w * 32 + x;

  U4B qfr;
  qfr.u = *(const uint4*)(qf + ((size_t)b * NDIM + qrow) * 16 + hi * 8);

  // per-lane base pointers; all loop offsets are compile-time immediates
  const uint16_t* kbase = kf + ((size_t)b * NDIM + sp * SPAN + x) * 16 + hi * 8;
  const uint16_t* vbase0 = vf + ((size_t)(b * 64 + x)) * NDIM + sp * SPAN + hi * 8;
  const uint16_t* vbase1 = vbase0 + (size_t)32 * NDIM;

  const f32x16 z16 = {0.f,0.f,0.f,0.f, 0.f,0.f,0.f,0.f,
                      0.f,0.f,0.f,0.f, 0.f,0.f,0.f,0.f};
  f32x16 oacc0 = z16, oacc1 = z16;
  float lacc[4] = {0.f, 0.f, 0.f, 0.f};

  // prologue: quarter-0 K and V fragments
  uint4 kc  = *(const uint4*)(kbase);
  uint4 vc0 = *(const uint4*)(vbase0);        // ch=x,    keys 0-15 slice
  uint4 vc1 = *(const uint4*)(vbase0 + 16);   // ch=x,    keys 16-31
  uint4 vd0 = *(const uint4*)(vbase1);        // ch=32+x, keys 0-15
  uint4 vd1 = *(const uint4*)(vbase1 + 16);   // ch=32+x, keys 16-31

#pragma unroll
  for (int gq = 0; gq < 16; gq++) {
    // ---- prefetch quarter gq+1 (final iteration overruns into adjacent
    // ws region: allocated memory, value dead)
    const int ko = (gq + 1) * 512;          // K: 32 keys x 16 elements
    const int vo = (gq + 1) * 32;           // V: 32 key elements
    uint4 kn  = *(const uint4*)(kbase + ko);
    uint4 vn0 = *(const uint4*)(vbase0 + vo);
    uint4 vn1 = *(const uint4*)(vbase0 + vo + 16);
    uint4 vm0 = *(const uint4*)(vbase1 + vo);
    uint4 vm1 = *(const uint4*)(vbase1 + vo + 16);

    // ---- scores S^T (32 keys x 32 queries), lane(q=x,hi):
    // key = (r&3) + 8*(r>>2) + 4hi
    U4B ka; ka.u = kc;
    f32x16 s = __builtin_amdgcn_mfma_f32_32x32x16_bf16(ka.b, qfr.b, z16, 0, 0, 0);

    // ---- fused p = exp2(s) -> bf16 pack -> row-sum (2 live p floats)
    uint32_t W[8];
#pragma unroll
    for (int j = 0; j < 8; j++) {
      const float p0 = fexp2(s[2 * j]);
      const float p1 = fexp2(s[2 * j + 1]);
      W[j] = cvtpk(p0, p1);
      lacc[j & 3] += p0 + p1;
    }

    // ---- PV: O^T += V^T . P^T (2 sub-chunks x 2 channel-blocks)
    __builtin_amdgcn_s_setprio(1);
    {
      uint32_t a0 = W[0], b0 = W[2], a1 = W[1], b1 = W[3];
      asm("v_permlane32_swap_b32 %0, %1" : "+v"(a0), "+v"(b0));
      asm("v_permlane32_swap_b32 %0, %1" : "+v"(a1), "+v"(b1));
      U4B pf, va, vb;
      pf.u = make_uint4(a0, a1, b0, b1);
      va.u = vc0; vb.u = vd0;
      oacc0 = __builtin_amdgcn_mfma_f32_32x32x16_bf16(va.b, pf.b, oacc0, 0, 0, 0);
      oacc1 = __builtin_amdgcn_mfma_f32_32x32x16_bf16(vb.b, pf.b, oacc1, 0, 0, 0);
    }
    {
      uint32_t a0 = W[4], b0 = W[6], a1 = W[5], b1 = W[7];
      asm("v_permlane32_swap_b32 %0, %1" : "+v"(a0), "+v"(b0));
      asm("v_permlane32_swap_b32 %0, %1" : "+v"(a1), "+v"(b1));
      U4B pf, va, vb;
      pf.u = make_uint4(a0, a1, b0, b1);
      va.u = vc1; vb.u = vd1;
      oacc0 = __builtin_amdgcn_mfma_f32_32x32x16_bf16(va.b, pf.b, oacc0, 0, 0, 0);
      oacc1 = __builtin_amdgcn_mfma_f32_32x32x16_bf16(vb.b, pf.b, oacc1, 0, 0, 0);
    }
    __builtin_amdgcn_s_setprio(0);

    kc = kn; vc0 = vn0; vc1 = vn1; vd0 = vm0; vd1 = vm1;
  }

  // ---- epilogue: raw (unnormalized) partial O in bf16 + row-sum l
  uint16_t* prow = po + (((size_t)sp * 4 + b) * NDIM + qrow) * CDIM;
#pragma unroll
  for (int cb = 0; cb < 2; cb++) {
    const f32x16 oa = (cb == 0) ? oacc0 : oacc1;
#pragma unroll
    for (int u = 0; u < 4; u++) {
      uint2 st;
      st.x = cvtpk(oa[u * 4 + 0], oa[u * 4 + 1]);
      st.y = cvtpk(oa[u * 4 + 2], oa[u * 4 + 3]);
      *(uint2*)(prow + cb * 32 + u * 8 + hi * 4) = st;
    }
  }
  float ltot = (lacc[0] + lacc[1]) + (lacc[2] + lacc[3]);
  ltot += __shfl_xor(ltot, 32);
  if (hi == 0)
    ls[((size_t)sp * 4 + b) * NDIM + qrow] = ltot;
}

// ---------------- Kernel 3: split merge + gamma*O + residual ----------------
// 512 blocks x 256 threads; block = (b, 32 queries); transpose via LDS.
// out = gamma * (sum_s po_s) / (sum_s l_s) + x_opt
__global__ __launch_bounds__(256) void merge_kernel(
    const uint16_t* __restrict__ po, const float* __restrict__ ls,
    const float* __restrict__ x_opt, const float* __restrict__ gamma,
    float* __restrict__ out)
{
  __shared__ float ot[32][65];
  const int tid = threadIdx.x;
  const int b = blockIdx.x >> 7;
  const int n0 = (blockIdx.x & 127) * 32;
  {
    const int q = tid >> 3;
    const int co = (tid & 7) * 8;
    const int nq = n0 + q;
    float wsum = 0.f;
    float acc[8] = {0.f, 0.f, 0.f, 0.f, 0.f, 0.f, 0.f, 0.f};
#pragma unroll
    for (int s = 0; s < NSPLIT; s++) {
      wsum += ls[((size_t)s * 4 + b) * NDIM + nq];
      const uint4 pv = *(const uint4*)(po + (((size_t)s * 4 + b) * NDIM + nq) * CDIM + co);
      const uint32_t* pw = (const uint32_t*)&pv;
#pragma unroll
      for (int j = 0; j < 4; j++) {
        acc[j * 2 + 0] += __uint_as_float(pw[j] << 16);
        acc[j * 2 + 1] += __uint_as_float(pw[j] & 0xFFFF0000u);
      }
    }
    const float inv = 1.f / wsum;
#pragma unroll
    for (int j = 0; j < 8; j++) ot[q][co + j] = acc[j] * inv;
  }
  __syncthreads();
  {
    const float gm = gamma[0];
    const int c = tid >> 2;
    const int j8 = (tid & 3) * 8;
    const float* xp = x_opt + ((size_t)b * CDIM + c) * NDIM + n0 + j8;
    float* op = out + ((size_t)b * CDIM + c) * NDIM + n0 + j8;
#pragma unroll
    for (int h = 0; h < 2; h++) {
      float4 xv = ((const float4*)xp)[h];
      float4 ov;
      ov.x = gm * ot[j8 + h * 4 + 0][c] + xv.x;
      ov.y = gm * ot[j8 + h * 4 + 1][c] + xv.y;
      ov.z = gm * ot[j8 + h * 4 + 2][c] + xv.z;
      ov.w = gm * ot[j8 + h * 4 + 3][c] + xv.w;
      ((float4*)op)[h] = ov;
    }
  }
}

extern "C" void kernel_launch(void* const* d_in, const int* in_sizes, int n_in,
                              void* d_out, int out_size, void* d_ws, size_t ws_size,
                              hipStream_t stream) {
  const float* x_opt = (const float*)d_in[0];
  const float* x_sar = (const float*)d_in[1];
  const float* wq    = (const float*)d_in[2];
  const float* bq    = (const float*)d_in[3];
  const float* wk    = (const float*)d_in[4];
  const float* bk    = (const float*)d_in[5];
  const float* wvp   = (const float*)d_in[6];
  const float* bv    = (const float*)d_in[7];
  const float* gamma = (const float*)d_in[8];
  float* outp = (float*)d_out;

  // ws: qf16 512K | kf16 512K | vf 2M | po(bf16) 16M | ls 512K  = 20.5MB
  uint16_t* qf = (uint16_t*)d_ws;
  uint16_t* kf = (uint16_t*)((char*)d_ws + 524288);
  uint16_t* vf = (uint16_t*)((char*)d_ws + 1048576);
  uint16_t* po = (uint16_t*)((char*)d_ws + 3145728);
  float* lsp   = (float*)((char*)d_ws + 19922944);

  proj_kernel<<<512, 256, 0, stream>>>(x_opt, x_sar, wq, bq, wk, bk, wvp, bv,
                                       qf, kf, vf);
  attn_kernel<<<1024, 256, 0, stream>>>(qf, kf, vf, po, lsp);
  merge_kernel<<<512, 256, 0, stream>>>(po, lsp, x_opt, gamma, outp);
}

// Round 11
// 37.558 us; speedup vs baseline: 1.4765x; 1.4765x over previous
//
#include <hip/hip_runtime.h>
#include <hip/hip_bf16.h>
#include <stdint.h>

#define NDIM 4096
#define CDIM 64
#define NSPLIT 8
#define SPAN (NDIM / NSPLIT)   // 512 keys per split
#define LOG2E 1.44269504088896f

typedef float f32x16 __attribute__((ext_vector_type(16)));
typedef short bf16x8 __attribute__((ext_vector_type(8)));
union U4B { uint4 u; bf16x8 b; };

// single-instruction packed f32->bf16 (RNE), lo -> bits[15:0], hi -> bits[31:16]
static __device__ __forceinline__ uint32_t cvtpk(float lo, float hi) {
  uint32_t r;
  asm("v_cvt_pk_bf16_f32 %0, %1, %2" : "=v"(r) : "v"(lo), "v"(hi));
  return r;
}
static __device__ __forceinline__ uint16_t f2bf(float f) {
  uint32_t r;
  asm("v_cvt_pk_bf16_f32 %0, %1, %1" : "=v"(r) : "v"(f));
  return (uint16_t)r;
}
static __device__ __forceinline__ float fexp2(float x) {
  return __builtin_amdgcn_exp2f(x);   // raw v_exp_f32
}

// ---------------- Kernel 1: projections via MFMA (fp32 -> bf16) -------------
// 512 blocks x 256 threads (4 waves). Block = (b, 32 columns); wave roles:
// w0: V rows 0-31, w1: V rows 32-63, w2: Q (from x_opt), w3: K (from x_sar).
// V written in key-blocked layout vf2[b][kb=key/16][ch][kk=key%16] so the
// attention kernel's V fragment loads are fully coalesced.
__global__ __launch_bounds__(256) void proj_kernel(
    const float* __restrict__ x_opt, const float* __restrict__ x_sar,
    const float* __restrict__ wq, const float* __restrict__ bq,
    const float* __restrict__ wk, const float* __restrict__ bk,
    const float* __restrict__ wvp, const float* __restrict__ bv,
    uint16_t* __restrict__ qf, uint16_t* __restrict__ kf,
    uint16_t* __restrict__ vf2)
{
  const int tid = threadIdx.x;
  const int w = tid >> 6;       // wave role
  const int l = tid & 63;
  const int x = l & 31;
  const int hi = l >> 5;

  const int id = blockIdx.x;
  const int b = id >> 7;
  const int n0 = (id & 127) * 32;
  const size_t xbase = (size_t)b * CDIM * NDIM;

  // ---- X B-fragment (lane = col n0+x, regs = 8 k along kc*16 + 8hi + j)
  const float* xsrc = (w == 2) ? x_opt : x_sar;
  bf16x8 xB[4];
#pragma unroll
  for (int kc = 0; kc < 4; kc++) {
    float sv[8];
#pragma unroll
    for (int j = 0; j < 8; j++)
      sv[j] = xsrc[xbase + (size_t)(kc * 16 + hi * 8 + j) * NDIM + n0 + x];
    U4B us;
    us.u = make_uint4(cvtpk(sv[0], sv[1]), cvtpk(sv[2], sv[3]),
                      cvtpk(sv[4], sv[5]), cvtpk(sv[6], sv[7]));
    xB[kc] = us.b;
  }

  // ---- W A-fragment
  bf16x8 aF[4];
#pragma unroll
  for (int kc = 0; kc < 4; kc++) {
    U4B ua;
    ua.u = make_uint4(0u, 0u, 0u, 0u);
    if (w < 2) {
      const float* wr = wvp + (w * 32 + x) * 64 + kc * 16 + hi * 8;
      float4 wa = ((const float4*)wr)[0];
      float4 wb = ((const float4*)wr)[1];
      ua.u = make_uint4(cvtpk(wa.x, wa.y), cvtpk(wa.z, wa.w),
                        cvtpk(wb.x, wb.y), cvtpk(wb.z, wb.w));
    } else if (x < 8) {
      const float* wr = ((w == 2) ? wq : wk) + x * 64 + kc * 16 + hi * 8;
      float4 wa = ((const float4*)wr)[0];
      float4 wb = ((const float4*)wr)[1];
      ua.u = make_uint4(cvtpk(wa.x, wa.y), cvtpk(wa.z, wa.w),
                        cvtpk(wb.x, wb.y), cvtpk(wb.z, wb.w));
    }
    aF[kc] = ua.b;
  }

  const f32x16 z16 = {0.f,0.f,0.f,0.f, 0.f,0.f,0.f,0.f,
                      0.f,0.f,0.f,0.f, 0.f,0.f,0.f,0.f};
  f32x16 acc = z16;
#pragma unroll
  for (int kc = 0; kc < 4; kc++)
    acc = __builtin_amdgcn_mfma_f32_32x32x16_bf16(aF[kc], xB[kc], acc, 0, 0, 0);

  if (w < 2) {
    // V stores into blocked layout: kb = (n0+x)/16, kk = (n0+x)%16
    const size_t kbbase = (size_t)b * 256 + (n0 >> 4) + (x >> 4);
    const int kk = x & 15;
#pragma unroll
    for (int r = 0; r < 16; r++) {
      const int row = w * 32 + (r & 3) + 8 * (r >> 2) + 4 * hi;
      vf2[(kbbase * 64 + row) * 16 + kk] = f2bf(acc[r] + bv[row]);
    }
  } else {
    // Q/K stores: regs 0-3 hold d = 4hi + r; layout [n][16], zero upper 8
    const float* bias = (w == 2) ? bq : bk;
    const float scl = (w == 2) ? LOG2E : 1.0f;   // q pre-scaled for exp2
    float gv[4];
#pragma unroll
    for (int r = 0; r < 4; r++) gv[r] = (acc[r] + bias[4 * hi + r]) * scl;
    uint16_t* dst = (w == 2) ? qf : kf;
    const size_t nrow = ((size_t)b * NDIM + n0 + x) * 16;
    uint2 st;
    st.x = cvtpk(gv[0], gv[1]); st.y = cvtpk(gv[2], gv[3]);
    *(uint2*)(dst + nrow + hi * 4) = st;
    if (hi == 0) {
      const uint4 z4 = make_uint4(0u, 0u, 0u, 0u);
      *(uint4*)(dst + nrow + 8) = z4;
    }
  }
}

// ------------- Kernel 2: flash attention partial (K-split) -----------
// 1024 blocks x 256 threads, sp = id&7 pins KV span to one XCD's L2.
// NO LDS, NO barriers. V in blocked layout vf2[b][kb][ch][kk]: each V
// fragment load is 64 lanes x 16B over one contiguous 2KB region (fully
// coalesced); K likewise. 1-quarter register lookahead hides L2 latency.
__global__ __launch_bounds__(256, 4) void attn_kernel(
    const uint16_t* __restrict__ qf, const uint16_t* __restrict__ kf,
    const uint16_t* __restrict__ vf2,
    uint16_t* __restrict__ po, float* __restrict__ ls)
{
  const int tid = threadIdx.x;
  const int w = tid >> 6;
  const int l = tid & 63;
  const int x = l & 31;       // query col (S,O) / key row (K-frag) / channel (V-frag)
  const int hi = l >> 5;

  const int id = blockIdx.x;
  const int sp = id & 7;
  const int qb = (id >> 3) & 31;
  const int b = id >> 8;

  const int n0 = qb * 128;
  const int qrow = n0 + w * 32 + x;

  U4B qfr;
  qfr.u = *(const uint4*)(qf + ((size_t)b * NDIM + qrow) * 16 + hi * 8);

  // per-lane bases; all loop offsets are compile-time immediates (u16 units)
  const uint16_t* kbase = kf + ((size_t)b * NDIM + sp * SPAN + x) * 16 + hi * 8;
  // vf2 idx: ((b*256 + sp*32 + kb)*64 + ch)*16 + kk; lane part: x*16 + 8hi
  const uint16_t* vbase =
      vf2 + (((size_t)b * 256 + sp * 32) * 64 + x) * 16 + hi * 8;
  // quarter q, sub s, chblock cb: offset = (2q+s)*1024 + cb*512

  const f32x16 z16 = {0.f,0.f,0.f,0.f, 0.f,0.f,0.f,0.f,
                      0.f,0.f,0.f,0.f, 0.f,0.f,0.f,0.f};
  f32x16 oacc0 = z16, oacc1 = z16;
  float lacc[4] = {0.f, 0.f, 0.f, 0.f};

  // prologue: quarter-0 K and V fragments
  uint4 kc   = *(const uint4*)(kbase);
  uint4 va00 = *(const uint4*)(vbase);           // sub0 ch 0-31
  uint4 va01 = *(const uint4*)(vbase + 512);     // sub0 ch 32-63
  uint4 va10 = *(const uint4*)(vbase + 1024);    // sub1 ch 0-31
  uint4 va11 = *(const uint4*)(vbase + 1536);    // sub1 ch 32-63

#pragma unroll
  for (int gq = 0; gq < 16; gq++) {
    // ---- prefetch quarter gq+1 (final iteration overruns into adjacent
    // ws region: allocated memory, value dead)
    const int vo = (gq + 1) * 2048;
    uint4 kn   = *(const uint4*)(kbase + (gq + 1) * 512);
    uint4 vn00 = *(const uint4*)(vbase + vo);
    uint4 vn01 = *(const uint4*)(vbase + vo + 512);
    uint4 vn10 = *(const uint4*)(vbase + vo + 1024);
    uint4 vn11 = *(const uint4*)(vbase + vo + 1536);

    // ---- scores S^T (32 keys x 32 queries), lane(q=x,hi):
    // key = (r&3) + 8*(r>>2) + 4hi
    U4B ka; ka.u = kc;
    f32x16 s = __builtin_amdgcn_mfma_f32_32x32x16_bf16(ka.b, qfr.b, z16, 0, 0, 0);

    // ---- fused p = exp2(s) -> bf16 pack -> row-sum (2 live p floats)
    uint32_t W[8];
#pragma unroll
    for (int j = 0; j < 8; j++) {
      const float p0 = fexp2(s[2 * j]);
      const float p1 = fexp2(s[2 * j + 1]);
      W[j] = cvtpk(p0, p1);
      lacc[j & 3] += p0 + p1;
    }

    // ---- PV: O^T += V^T . P^T (2 sub-chunks x 2 channel-blocks)
    __builtin_amdgcn_s_setprio(1);
    {
      uint32_t a0 = W[0], b0 = W[2], a1 = W[1], b1 = W[3];
      asm("v_permlane32_swap_b32 %0, %1" : "+v"(a0), "+v"(b0));
      asm("v_permlane32_swap_b32 %0, %1" : "+v"(a1), "+v"(b1));
      U4B pf, va, vb;
      pf.u = make_uint4(a0, a1, b0, b1);
      va.u = va00; vb.u = va01;
      oacc0 = __builtin_amdgcn_mfma_f32_32x32x16_bf16(va.b, pf.b, oacc0, 0, 0, 0);
      oacc1 = __builtin_amdgcn_mfma_f32_32x32x16_bf16(vb.b, pf.b, oacc1, 0, 0, 0);
    }
    {
      uint32_t a0 = W[4], b0 = W[6], a1 = W[5], b1 = W[7];
      asm("v_permlane32_swap_b32 %0, %1" : "+v"(a0), "+v"(b0));
      asm("v_permlane32_swap_b32 %0, %1" : "+v"(a1), "+v"(b1));
      U4B pf, va, vb;
      pf.u = make_uint4(a0, a1, b0, b1);
      va.u = va10; vb.u = va11;
      oacc0 = __builtin_amdgcn_mfma_f32_32x32x16_bf16(va.b, pf.b, oacc0, 0, 0, 0);
      oacc1 = __builtin_amdgcn_mfma_f32_32x32x16_bf16(vb.b, pf.b, oacc1, 0, 0, 0);
    }
    __builtin_amdgcn_s_setprio(0);

    kc = kn; va00 = vn00; va01 = vn01; va10 = vn10; va11 = vn11;
  }

  // ---- epilogue: raw (unnormalized) partial O in bf16 + row-sum l
  uint16_t* prow = po + (((size_t)sp * 4 + b) * NDIM + qrow) * CDIM;
#pragma unroll
  for (int cb = 0; cb < 2; cb++) {
    const f32x16 oa = (cb == 0) ? oacc0 : oacc1;
#pragma unroll
    for (int u = 0; u < 4; u++) {
      uint2 st;
      st.x = cvtpk(oa[u * 4 + 0], oa[u * 4 + 1]);
      st.y = cvtpk(oa[u * 4 + 2], oa[u * 4 + 3]);
      *(uint2*)(prow + cb * 32 + u * 8 + hi * 4) = st;
    }
  }
  float ltot = (lacc[0] + lacc[1]) + (lacc[2] + lacc[3]);
  ltot += __shfl_xor(ltot, 32);
  if (hi == 0)
    ls[((size_t)sp * 4 + b) * NDIM + qrow] = ltot;
}

// ---------------- Kernel 3: split merge + gamma*O + residual ----------------
// 512 blocks x 256 threads; block = (b, 32 queries); transpose via LDS.
// out = gamma * (sum_s po_s) / (sum_s l_s) + x_opt
__global__ __launch_bounds__(256) void merge_kernel(
    const uint16_t* __restrict__ po, const float* __restrict__ ls,
    const float* __restrict__ x_opt, const float* __restrict__ gamma,
    float* __restrict__ out)
{
  __shared__ float ot[32][65];
  const int tid = threadIdx.x;
  const int b = blockIdx.x >> 7;
  const int n0 = (blockIdx.x & 127) * 32;
  {
    const int q = tid >> 3;
    const int co = (tid & 7) * 8;
    const int nq = n0 + q;
    float wsum = 0.f;
    float acc[8] = {0.f, 0.f, 0.f, 0.f, 0.f, 0.f, 0.f, 0.f};
#pragma unroll
    for (int s = 0; s < NSPLIT; s++) {
      wsum += ls[((size_t)s * 4 + b) * NDIM + nq];
      const uint4 pv = *(const uint4*)(po + (((size_t)s * 4 + b) * NDIM + nq) * CDIM + co);
      const uint32_t* pw = (const uint32_t*)&pv;
#pragma unroll
      for (int j = 0; j < 4; j++) {
        acc[j * 2 + 0] += __uint_as_float(pw[j] << 16);
        acc[j * 2 + 1] += __uint_as_float(pw[j] & 0xFFFF0000u);
      }
    }
    const float inv = 1.f / wsum;
#pragma unroll
    for (int j = 0; j < 8; j++) ot[q][co + j] = acc[j] * inv;
  }
  __syncthreads();
  {
    const float gm = gamma[0];
    const int c = tid >> 2;
    const int j8 = (tid & 3) * 8;
    const float* xp = x_opt + ((size_t)b * CDIM + c) * NDIM + n0 + j8;
    float* op = out + ((size_t)b * CDIM + c) * NDIM + n0 + j8;
#pragma unroll
    for (int h = 0; h < 2; h++) {
      float4 xv = ((const float4*)xp)[h];
      float4 ov;
      ov.x = gm * ot[j8 + h * 4 + 0][c] + xv.x;
      ov.y = gm * ot[j8 + h * 4 + 1][c] + xv.y;
      ov.z = gm * ot[j8 + h * 4 + 2][c] + xv.z;
      ov.w = gm * ot[j8 + h * 4 + 3][c] + xv.w;
      ((float4*)op)[h] = ov;
    }
  }
}

extern "C" void kernel_launch(void* const* d_in, const int* in_sizes, int n_in,
                              void* d_out, int out_size, void* d_ws, size_t ws_size,
                              hipStream_t stream) {
  const float* x_opt = (const float*)d_in[0];
  const float* x_sar = (const float*)d_in[1];
  const float* wq    = (const float*)d_in[2];
  const float* bq    = (const float*)d_in[3];
  const float* wk    = (const float*)d_in[4];
  const float* bk    = (const float*)d_in[5];
  const float* wvp   = (const float*)d_in[6];
  const float* bv    = (const float*)d_in[7];
  const float* gamma = (const float*)d_in[8];
  float* outp = (float*)d_out;

  // ws: qf16 512K | kf16 512K | vf2 2M | po(bf16) 16M | ls 512K  = 20.5MB
  uint16_t* qf  = (uint16_t*)d_ws;
  uint16_t* kf  = (uint16_t*)((char*)d_ws + 524288);
  uint16_t* vf2 = (uint16_t*)((char*)d_ws + 1048576);
  uint16_t* po  = (uint16_t*)((char*)d_ws + 3145728);
  float* lsp    = (float*)((char*)d_ws + 19922944);

  proj_kernel<<<512, 256, 0, stream>>>(x_opt, x_sar, wq, bq, wk, bk, wvp, bv,
                                       qf, kf, vf2);
  attn_kernel<<<1024, 256, 0, stream>>>(qf, kf, vf2, po, lsp);
  merge_kernel<<<512, 256, 0, stream>>>(po, lsp, x_opt, gamma, outp);
}